// Round 15
// baseline (285.417 us; speedup 1.0000x reference)
//
#include <hip/hip_runtime.h>
#include <hip/hip_bf16.h>

#define H_IMG 224
#define W_IMG 224
#define B_ 4
#define C_ 256
#define M_ 1024
#define N_ 16384
#define HW_ (H_IMG * W_IMG)
#define OH_ 56
#define OW_ 56
#define NBLK_ (OH_ * OW_)        // 3136 pool blocks per batch
#define NBINS_ (B_ * NBLK_)      // 12544 total bins
#define NT_ (B_ * N_)            // 65536 total points
#define SEG_ 32                  // max points per gather segment
#define MAXSEG_ (NBINS_ + NT_ / SEG_)   // 14592 upper bound
#define KS_ 8                    // center-dimension slices in top3
#define MC_ (M_ / KS_)           // 128 centers per slice
#define PTS_ 64                  // points per top3 block
#define TPB3_ (PTS_ * KS_)       // 512 threads per top3 block
#define NBLK3_ (B_ * N_ / PTS_)  // 1024 top3 blocks
#define SPER_ ((NBINS_ + TPB3_ - 1) / TPB3_)   // 25 bins per scan thread
// contiguous zero region: tmp + cnt + binCnt + binFill + segTotal + doneCnt
#define ZTOT_ (NBINS_ * C_ + B_ * HW_ + 2 * NBINS_ + 2)

// ------- Kernel A: transpose xyz_feats (B,C,M)->XT (B,M,C) + fused zeroing -
__global__ __launch_bounds__(1024) void transpose_kernel(
    const float* __restrict__ xyz, float* __restrict__ XT,
    float* __restrict__ zeroRegion)
{
    __shared__ float tile[32][33];
    int b  = blockIdx.z;
    int c0 = blockIdx.x * 32;
    int m0 = blockIdx.y * 32;
    int tx = threadIdx.x, ty = threadIdx.y;
    int flat = ((blockIdx.z * gridDim.y + blockIdx.y) * gridDim.x + blockIdx.x)
               * 1024 + ty * 32 + tx;
    for (int i = flat; i < ZTOT_; i += 1024 * 1024) zeroRegion[i] = 0.0f;
    tile[ty][tx] = xyz[(b * C_ + c0 + ty) * M_ + m0 + tx];
    __syncthreads();
    XT[(b * M_ + m0 + ty) * C_ + c0 + tx] = tile[tx][ty];
}

// -------- Kernel B: top-3 NN (1024 blk x 512 thr) + TAIL-FUSED scan --------
// NUMERICS LOCKED (R7 pass): np ref einsum tail is DESCENDING-index separate
// mul/add: dot = ((pz*cz)+(py*cy))+(px*cx); p2/c2 ascending; d=(p2+c2)-2*dot;
// contract(off); stable top-3 (lowest index on exact ties); projection
// order-invariant. DO NOT change any decision arithmetic.
// R14 postmortem: top3 duration invariant (~59us) across 3 formulations at
// ~46 VALU instrs/pair -> source-level floor reached. This round attacks the
// OTHER 128us: (a) last-block tail-fuses the scan (one fewer launch+gap;
// no grid.sync -- only the final block proceeds, standard fence+counter);
// (b) 512-thr blocks, 4 blocks/CU for finer ramp/tail (same 32 waves/CU).
// Min/max-network insert proven bit-identical in R14 (passed).
__global__ __launch_bounds__(TPB3_, 8) void top3_kernel(
    const float* __restrict__ points, const float* __restrict__ centers,
    const float* __restrict__ Kmat,
    int* __restrict__ pixA, int* __restrict__ idA, float* __restrict__ wA,
    float* __restrict__ cnt, int* __restrict__ binCnt,
    int* __restrict__ binOff, int4* __restrict__ segs,
    int* __restrict__ segTotal, int* __restrict__ doneCnt)
{
#pragma clang fp contract(off)
    __shared__ float4 cen[M_];            // 16 KB
    __shared__ float  pd[KS_][PTS_][3];   // 6 KB partial distances
    __shared__ int    pi[KS_][PTS_][3];   // 6 KB partial indices
    __shared__ int    isLast;
    int b     = blockIdx.y;
    int t     = threadIdx.x;
    int pl    = t & (PTS_ - 1);           // point lane
    int s     = t >> 6;                   // slice
    int nbase = blockIdx.x * PTS_;

    for (int i = t; i < M_; i += TPB3_) { // stage centers (2 per thread)
        const float* cb = centers + (size_t)(b * M_ + i) * 3;
        float cx = cb[0], cy = cb[1], cz = cb[2];
        float c2 = ((cx * cx) + (cy * cy)) + (cz * cz);   // np.sum ascending
        cen[i] = make_float4(cx, cy, cz, c2);
    }
    __syncthreads();

    int g0 = b * N_ + nbase + pl;
    const float* pp = points + (size_t)g0 * 3;
    float px = pp[0], py = pp[1], pz = pp[2];
    float p2 = ((px * px) + (py * py)) + (pz * pz);       // np.sum ascending

    float d0 = 1e30f, d1 = 1e30f, d2v = 1e30f;
    int   i0 = 0, i1 = 0, i2 = 0;
    int mbase = s * MC_;
#pragma unroll 4
    for (int j = 0; j < MC_; ++j) {
        int m = mbase + j;
        float4 cc = cen[m];               // uniform in wave: LDS broadcast
        float dot = ((pz * cc.z) + (py * cc.y)) + (px * cc.x); // np tail order
        float d   = (p2 + cc.w) - (2.0f * dot);
        // stable sorted-insert min/max network (R14-proven bit-identical)
        bool  c0  = d < d0;
        float l0  = fmaxf(d, d0);
        int   li0 = c0 ? i0 : m;
        d0 = fminf(d, d0);
        i0 = c0 ? m : i0;
        bool  c1  = l0 < d1;
        float l1  = fmaxf(l0, d1);
        int   li1 = c1 ? i1 : li0;
        d1 = fminf(l0, d1);
        i1 = c1 ? li0 : i1;
        bool  c2  = l1 < d2v;
        d2v = fminf(l1, d2v);
        i2  = c2 ? li1 : i2;
    }
    pd[s][pl][0] = d0;  pd[s][pl][1] = d1;  pd[s][pl][2] = d2v;
    pi[s][pl][0] = i0;  pi[s][pl][1] = i1;  pi[s][pl][2] = i2;
    __syncthreads();

    if (t < PTS_) {
        // merge 24 candidates, full lexicographic (d, idx): order-independent
        float md0 = 1e30f, md1 = 1e30f, md2 = 1e30f;
        int   mi0 = M_,    mi1 = M_,    mi2 = M_;
#pragma unroll
        for (int ss = 0; ss < KS_; ++ss)
#pragma unroll
            for (int j = 0; j < 3; ++j) {
                float dd = pd[ss][t][j];
                int   ii = pi[ss][t][j];
                if ((dd < md2) || (dd == md2 && ii < mi2)) {
                    if ((dd < md1) || (dd == md1 && ii < mi1)) {
                        md2 = md1; mi2 = mi1;
                        if ((dd < md0) || (dd == md0 && ii < mi0)) {
                            md1 = md0; mi1 = mi0; md0 = dd; mi0 = ii;
                        } else { md1 = dd; mi1 = ii; }
                    } else { md2 = dd; mi2 = ii; }
                }
            }

        float w0 = 1.0f / (md0 + 1e-8f);
        float w1 = 1.0f / (md1 + 1e-8f);
        float w2 = 1.0f / (md2 + 1e-8f);
        float ws = (w0 + w1) + w2;
        w0 /= ws; w1 /= ws; w2 /= ws;

        int g = b * N_ + nbase + t;
        const float* pq = points + (size_t)g * 3;
        float qx = pq[0], qy = pq[1], qz = pq[2];
        // projection: order-invariant (single add of two products; 0*py exact)
        float fx = Kmat[0], cxk = Kmat[2], fy = Kmat[4], cyk = Kmat[5];
        float u_num = (cxk * qz) + (fx * qx);
        float v_num = (cyk * qz) + (fy * qy);
        float zc    = fmaxf(qz, 1e-8f);
        float u = floorf(u_num / zc);
        float v = floorf(v_num / zc);
        int ui = (int)fminf(fmaxf(u, 0.0f), (float)(W_IMG - 1));
        int vi = (int)fminf(fmaxf(v, 0.0f), (float)(H_IMG - 1));
        int pix = vi * W_IMG + ui;

        pixA[g] = pix;
        idA[g]           = mi0; idA[g + NT_]     = mi1; idA[g + 2 * NT_] = mi2;
        wA [g]           = w0;  wA [g + NT_]     = w1;  wA [g + 2 * NT_] = w2;
        atomicAdd(&cnt[b * HW_ + pix], 1.0f);
        int bin = b * NBLK_ + (vi >> 2) * OW_ + (ui >> 2);
        atomicAdd(&binCnt[bin], 1);
    }

    // ---------- tail-fused scan + seg emit: only the LAST block runs -------
    __syncthreads();
    __threadfence();                       // release this block's writes
    if (t == 0) {
        int prev = atomicAdd(doneCnt, 1);
        isLast = (prev == NBLK3_ - 1);
    }
    __syncthreads();
    if (!isLast) return;
    __threadfence();                       // acquire all blocks' writes

    // dual exclusive scan over (k, nseg); no per-thread arrays (low VGPR):
    // pass 1 sums, Hillis-Steele over 512 partials, pass 2 recomputes + emits.
    int* partK = &pi[0][0][0];             // reuse LDS (12 KB total, need 4)
    int* partS = partK + TPB3_;
    int base = t * SPER_;
    int sk = 0, sn = 0;
    for (int j = 0; j < SPER_; ++j) {
        int idx = base + j;
        if (idx < NBINS_) {
            int k = binCnt[idx];
            int ns = (k + SEG_ - 1) / SEG_; if (ns == 0) ns = 1;
            sk += k; sn += ns;
        }
    }
    partK[t] = sk; partS[t] = sn;
    __syncthreads();
    for (int ofs = 1; ofs < TPB3_; ofs <<= 1) {
        int vK = (t >= ofs) ? partK[t - ofs] : 0;
        int vS = (t >= ofs) ? partS[t - ofs] : 0;
        __syncthreads();
        partK[t] += vK; partS[t] += vS;
        __syncthreads();
    }
    int runK = (t == 0) ? 0 : partK[t - 1];
    int runS = (t == 0) ? 0 : partS[t - 1];
    for (int j = 0; j < SPER_; ++j) {
        int idx = base + j;
        if (idx >= NBINS_) continue;
        int k = binCnt[idx];
        int ns = (k + SEG_ - 1) / SEG_; if (ns == 0) ns = 1;
        binOff[idx] = runK;
        for (int q = 0; q < ns; ++q) {
            int len = k - q * SEG_;
            len = (len < 0) ? 0 : ((len > SEG_) ? SEG_ : len);
            segs[runS + q] = make_int4(idx, runK + q * SEG_, len, ns);
        }
        runK += k; runS += ns;
    }
    if (t == TPB3_ - 1) segTotal[0] = partS[TPB3_ - 1];
}

// ---------------- Kernel P: pack points into bin order, pre-scale weights --
__global__ __launch_bounds__(256) void pack_kernel(
    const int* __restrict__ pixA, const int* __restrict__ idA,
    const float* __restrict__ wA, const float* __restrict__ cnt,
    const int* __restrict__ binOff, int* __restrict__ binFill,
    int4* __restrict__ idP, float4* __restrict__ wP)
{
    int g = blockIdx.x * 256 + threadIdx.x;
    int b = g >> 14;                     // N_ = 16384
    int pix = pixA[g];
    int u = pix % W_IMG, v = pix / W_IMG;
    int bin = b * NBLK_ + (v >> 2) * OW_ + (u >> 2);
    int pos = atomicAdd(&binFill[bin], 1);
    int dst = binOff[bin] + pos;
    float s = 0.0625f / fmaxf(cnt[b * HW_ + pix], 1.0f);
    idP[dst] = make_int4(idA[g], idA[g + NT_], idA[g + 2 * NT_], b);
    wP[dst]  = make_float4(wA[g] * s, wA[g + NT_] * s, wA[g + 2 * NT_] * s, 0.0f);
}

// ---------------- Kernel G: per-segment gather-reduce into bin-major tmp ---
// Bin-major stores: 64 consecutive lanes = contiguous 1KB => zero inflation.
// 4 accumulators + unroll-4: ~12 gather loads in flight (L2-latency hiding).
__global__ __launch_bounds__(256) void gather_kernel(
    const float* __restrict__ XT, const int4* __restrict__ segs,
    const int* __restrict__ segTotal, const int4* __restrict__ idP,
    const float4* __restrict__ wP, float* __restrict__ tmp)
{
    int sid = blockIdx.x;
    if (sid >= segTotal[0]) return;
    int4 sg   = segs[sid];
    int bin   = sg.x, start = sg.y, len = sg.z, nseg = sg.w;
    int b     = bin / NBLK_;
    int c     = threadIdx.x;

    __shared__ int4   sId[SEG_];
    __shared__ float4 sW [SEG_];
    if (c < len) { sId[c] = idP[start + c]; sW[c] = wP[start + c]; }
    __syncthreads();

    const float* XTb = XT + (size_t)b * (M_ * C_);
    float a0 = 0.0f, a1 = 0.0f, a2 = 0.0f, a3 = 0.0f;
    int j = 0;
    for (; j + 3 < len; j += 4) {
        int4 iA = sId[j];     float4 wAa = sW[j];
        int4 iB = sId[j + 1]; float4 wBb = sW[j + 1];
        int4 iC = sId[j + 2]; float4 wCc = sW[j + 2];
        int4 iD = sId[j + 3]; float4 wDd = sW[j + 3];
        a0 = fmaf(wAa.x, XTb[iA.x * C_ + c],
             fmaf(wAa.y, XTb[iA.y * C_ + c],
             fmaf(wAa.z, XTb[iA.z * C_ + c], a0)));
        a1 = fmaf(wBb.x, XTb[iB.x * C_ + c],
             fmaf(wBb.y, XTb[iB.y * C_ + c],
             fmaf(wBb.z, XTb[iB.z * C_ + c], a1)));
        a2 = fmaf(wCc.x, XTb[iC.x * C_ + c],
             fmaf(wCc.y, XTb[iC.y * C_ + c],
             fmaf(wCc.z, XTb[iC.z * C_ + c], a2)));
        a3 = fmaf(wDd.x, XTb[iD.x * C_ + c],
             fmaf(wDd.y, XTb[iD.y * C_ + c],
             fmaf(wDd.z, XTb[iD.z * C_ + c], a3)));
    }
    for (; j < len; ++j) {
        int4 iA = sId[j]; float4 wAa = sW[j];
        a0 = fmaf(wAa.x, XTb[iA.x * C_ + c],
             fmaf(wAa.y, XTb[iA.y * C_ + c],
             fmaf(wAa.z, XTb[iA.z * C_ + c], a0)));
    }
    float acc = (a0 + a1) + (a2 + a3);

    float* dst = &tmp[(size_t)bin * C_ + c];
    if (nseg == 1) *dst = acc;            // covers empty bins (acc = 0)
    else           atomicAdd(dst, acc);   // tmp pre-zeroed in transpose_kernel
}

// ---------------- Kernel U: untranspose tmp (B,NBLK,C) -> out (B,C,NBLK) ---
__global__ __launch_bounds__(1024) void untranspose_kernel(
    const float* __restrict__ tmp, float* __restrict__ out)
{
    __shared__ float tile[32][33];
    int b  = blockIdx.z;
    int n0 = blockIdx.x * 32;   // NBLK_/32 = 98
    int c0 = blockIdx.y * 32;   // C_/32 = 8
    int tx = threadIdx.x, ty = threadIdx.y;
    tile[ty][tx] = tmp[((size_t)b * NBLK_ + n0 + ty) * C_ + c0 + tx];
    __syncthreads();
    out[((size_t)(b * C_ + c0 + ty)) * NBLK_ + n0 + tx] = tile[tx][ty];
}

extern "C" void kernel_launch(void* const* d_in, const int* in_sizes, int n_in,
                              void* d_out, int out_size, void* d_ws, size_t ws_size,
                              hipStream_t stream)
{
    const float* xyz_feats = (const float*)d_in[0];  // (B,C,M)
    const float* points    = (const float*)d_in[1];  // (B,N,3)
    const float* centers   = (const float*)d_in[2];  // (B,M,3)
    const float* Kmat      = (const float*)d_in[3];  // (3,3)

    float* out = (float*)d_out;

    // workspace layout (~21.7 MB); zero region: tmp..doneCnt contiguous
    float*  XT       = (float*)d_ws;                         // 4 MB
    int4*   idP      = (int4*)(XT + (size_t)B_ * M_ * C_);   // 1 MB
    float4* wP       = (float4*)(idP + NT_);                 // 1 MB
    int4*   segs     = (int4*)(wP + NT_);                    // 228 KB
    float*  tmp      = (float*)(segs + MAXSEG_);             // 12.8 MB (zero rgn)
    float*  cnt      = tmp + (size_t)NBINS_ * C_;            // 784 KB
    int*    binCnt   = (int*)(cnt + (size_t)B_ * HW_);       // 50 KB
    int*    binFill  = binCnt + NBINS_;                      // 50 KB
    int*    segTotal = binFill + NBINS_;                     // 4 B
    int*    doneCnt  = segTotal + 1;                         // 4 B
    int*    pixA     = doneCnt + 1;                          // 256 KB
    int*    idA      = pixA + NT_;                           // 768 KB
    float*  wA       = (float*)(idA + 3 * NT_);              // 768 KB
    int*    binOff   = (int*)(wA + 3 * NT_);                 // 50 KB

    dim3 tb(32, 32);
    dim3 tg(C_ / 32, M_ / 32, B_);
    transpose_kernel<<<tg, tb, 0, stream>>>(xyz_feats, XT, tmp);

    dim3 bg(N_ / PTS_, B_);   // 256 x 4 = 1024 blocks, 4 blocks/CU
    top3_kernel<<<bg, TPB3_, 0, stream>>>(points, centers, Kmat,
                                          pixA, idA, wA, cnt, binCnt,
                                          binOff, segs, segTotal, doneCnt);

    pack_kernel<<<NT_ / 256, 256, 0, stream>>>(pixA, idA, wA, cnt,
                                               binOff, binFill, idP, wP);

    gather_kernel<<<MAXSEG_, 256, 0, stream>>>(XT, segs, segTotal,
                                               idP, wP, tmp);

    dim3 ug(NBLK_ / 32, C_ / 32, B_);
    untranspose_kernel<<<ug, tb, 0, stream>>>(tmp, out);
}

// Round 16
// 186.353 us; speedup vs baseline: 1.5316x; 1.5316x over previous
//
#include <hip/hip_runtime.h>
#include <hip/hip_bf16.h>

#define H_IMG 224
#define W_IMG 224
#define B_ 4
#define C_ 256
#define M_ 1024
#define N_ 16384
#define HW_ (H_IMG * W_IMG)
#define OH_ 56
#define OW_ 56
#define NBLK_ (OH_ * OW_)        // 3136 pool blocks per batch
#define NBINS_ (B_ * NBLK_)      // 12544 total bins
#define NT_ (B_ * N_)            // 65536 total points
#define SEG_ 32                  // max points per gather segment
#define MAXSEG_ (NBINS_ + NT_ / SEG_)   // 14592 upper bound
#define KS_ 8                    // center-dimension slices in top3
#define MC_ (M_ / KS_)           // 128 centers per slice
#define PTS_ 128                 // points per top3 block
// contiguous zero region: tmp + cnt + binCnt + binFill + segTotal
#define ZTOT_ (NBINS_ * C_ + B_ * HW_ + 2 * NBINS_ + 1)

// ------- Kernel A: transpose xyz_feats (B,C,M)->XT (B,M,C) + fused zeroing -
__global__ __launch_bounds__(1024) void transpose_kernel(
    const float* __restrict__ xyz, float* __restrict__ XT,
    float* __restrict__ zeroRegion)
{
    __shared__ float tile[32][33];
    int b  = blockIdx.z;
    int c0 = blockIdx.x * 32;
    int m0 = blockIdx.y * 32;
    int tx = threadIdx.x, ty = threadIdx.y;
    int flat = ((blockIdx.z * gridDim.y + blockIdx.y) * gridDim.x + blockIdx.x)
               * 1024 + ty * 32 + tx;
    for (int i = flat; i < ZTOT_; i += 1024 * 1024) zeroRegion[i] = 0.0f;
    tile[ty][tx] = xyz[(b * C_ + c0 + ty) * M_ + m0 + tx];
    __syncthreads();
    XT[(b * M_ + m0 + ty) * C_ + c0 + tx] = tile[tx][ty];
}

// -------- Kernel B: top-3 NN, 512 blocks x (128 pts x 8 slices) ------------
// NUMERICS LOCKED (R7 pass): np ref einsum tail is DESCENDING-index separate
// mul/add: dot = ((pz*cz)+(py*cy))+(px*cx); p2/c2 ascending; d=(p2+c2)-2*dot;
// contract(off); stable top-3 (lowest index on exact ties); projection
// order-invariant. DO NOT change any decision arithmetic.
// STRUCTURE LOCKED (R12/R15 lessons): NO intra-kernel cross-block sync on
// MI355X -- grid.sync (R12: 187->348us) and threadfence+done-counter (R15:
// top3 59->185us, VALUBusy 67->23%: per-block device fences = XCD L2
// writeback storm) both regress badly. Kernel boundaries are the cheap sync.
// This is exactly R14's proven 59us configuration.
__global__ __launch_bounds__(1024, 8) void top3_kernel(
    const float* __restrict__ points, const float* __restrict__ centers,
    const float* __restrict__ Kmat,
    int* __restrict__ pixA, int* __restrict__ idA, float* __restrict__ wA,
    float* __restrict__ cnt, int* __restrict__ binCnt)
{
#pragma clang fp contract(off)
    __shared__ float4 cen[M_];            // 16 KB
    __shared__ float  pd[KS_][PTS_][3];   // 12 KB partial distances
    __shared__ int    pi[KS_][PTS_][3];   // 12 KB partial indices
    int b     = blockIdx.y;
    int t     = threadIdx.x;
    int pl    = t & 127;                  // point lane
    int s     = t >> 7;                   // slice
    int nbase = blockIdx.x * PTS_;

    {   // stage centers: one per thread (t in [0,1024) == M_)
        const float* cb = centers + (size_t)(b * M_ + t) * 3;
        float cx = cb[0], cy = cb[1], cz = cb[2];
        float c2 = ((cx * cx) + (cy * cy)) + (cz * cz);   // np.sum ascending
        cen[t] = make_float4(cx, cy, cz, c2);
    }
    __syncthreads();

    int g0 = b * N_ + nbase + pl;
    const float* pp = points + (size_t)g0 * 3;
    float px = pp[0], py = pp[1], pz = pp[2];
    float p2 = ((px * px) + (py * py)) + (pz * pz);       // np.sum ascending

    float d0 = 1e30f, d1 = 1e30f, d2v = 1e30f;
    int   i0 = 0, i1 = 0, i2 = 0;
    int mbase = s * MC_;
#pragma unroll 4
    for (int j = 0; j < MC_; ++j) {
        int m = mbase + j;
        float4 cc = cen[m];               // uniform in wave: LDS broadcast
        float dot = ((pz * cc.z) + (py * cc.y)) + (px * cc.x); // np tail order
        float d   = (p2 + cc.w) - (2.0f * dot);
        // stable sorted-insert min/max network (R14-proven bit-identical)
        bool  c0  = d < d0;
        float l0  = fmaxf(d, d0);         // loser value
        int   li0 = c0 ? i0 : m;          // loser idx (incumbent wins tie)
        d0 = fminf(d, d0);
        i0 = c0 ? m : i0;
        bool  c1  = l0 < d1;
        float l1  = fmaxf(l0, d1);
        int   li1 = c1 ? i1 : li0;
        d1 = fminf(l0, d1);
        i1 = c1 ? li0 : i1;
        bool  c2  = l1 < d2v;
        d2v = fminf(l1, d2v);
        i2  = c2 ? li1 : i2;
    }
    pd[s][pl][0] = d0;  pd[s][pl][1] = d1;  pd[s][pl][2] = d2v;
    pi[s][pl][0] = i0;  pi[s][pl][1] = i1;  pi[s][pl][2] = i2;
    __syncthreads();

    if (t < PTS_) {
        // merge 24 candidates, full lexicographic (d, idx): order-independent
        float md0 = 1e30f, md1 = 1e30f, md2 = 1e30f;
        int   mi0 = M_,    mi1 = M_,    mi2 = M_;
#pragma unroll
        for (int ss = 0; ss < KS_; ++ss)
#pragma unroll
            for (int j = 0; j < 3; ++j) {
                float dd = pd[ss][t][j];
                int   ii = pi[ss][t][j];
                if ((dd < md2) || (dd == md2 && ii < mi2)) {
                    if ((dd < md1) || (dd == md1 && ii < mi1)) {
                        md2 = md1; mi2 = mi1;
                        if ((dd < md0) || (dd == md0 && ii < mi0)) {
                            md1 = md0; mi1 = mi0; md0 = dd; mi0 = ii;
                        } else { md1 = dd; mi1 = ii; }
                    } else { md2 = dd; mi2 = ii; }
                }
            }

        float w0 = 1.0f / (md0 + 1e-8f);
        float w1 = 1.0f / (md1 + 1e-8f);
        float w2 = 1.0f / (md2 + 1e-8f);
        float ws = (w0 + w1) + w2;
        w0 /= ws; w1 /= ws; w2 /= ws;

        int g = b * N_ + nbase + t;
        const float* pq = points + (size_t)g * 3;
        float qx = pq[0], qy = pq[1], qz = pq[2];
        // projection: order-invariant (single add of two products; 0*py exact)
        float fx = Kmat[0], cxk = Kmat[2], fy = Kmat[4], cyk = Kmat[5];
        float u_num = (cxk * qz) + (fx * qx);
        float v_num = (cyk * qz) + (fy * qy);
        float zc    = fmaxf(qz, 1e-8f);
        float u = floorf(u_num / zc);
        float v = floorf(v_num / zc);
        int ui = (int)fminf(fmaxf(u, 0.0f), (float)(W_IMG - 1));
        int vi = (int)fminf(fmaxf(v, 0.0f), (float)(H_IMG - 1));
        int pix = vi * W_IMG + ui;

        pixA[g] = pix;
        idA[g]           = mi0; idA[g + NT_]     = mi1; idA[g + 2 * NT_] = mi2;
        wA [g]           = w0;  wA [g + NT_]     = w1;  wA [g + 2 * NT_] = w2;
        atomicAdd(&cnt[b * HW_ + pix], 1.0f);
        int bin = b * NBLK_ + (vi >> 2) * OW_ + (ui >> 2);
        atomicAdd(&binCnt[bin], 1);
    }
}

// ------- Kernel S: dual exclusive scan (k, nseg) + deterministic seg emit --
__global__ __launch_bounds__(1024) void scan_kernel(
    const int* __restrict__ binCnt, int* __restrict__ binOff,
    int4* __restrict__ segs, int* __restrict__ segTotal)
{
    const int PER = (NBINS_ + 1023) / 1024;   // 13
    __shared__ int partK[1024], partS[1024];
    int t = threadIdx.x;
    int base = t * PER;
    int localK[PER], localS[PER];
    int sk = 0, sn = 0;
#pragma unroll
    for (int j = 0; j < PER; ++j) {
        int idx = base + j;
        int k  = (idx < NBINS_) ? binCnt[idx] : 0;
        int ns = 0;
        if (idx < NBINS_) { ns = (k + SEG_ - 1) / SEG_; if (ns == 0) ns = 1; }
        localK[j] = sk; localS[j] = sn;
        sk += k; sn += ns;
    }
    partK[t] = sk; partS[t] = sn;
    __syncthreads();
    for (int ofs = 1; ofs < 1024; ofs <<= 1) {
        int vK = (t >= ofs) ? partK[t - ofs] : 0;
        int vS = (t >= ofs) ? partS[t - ofs] : 0;
        __syncthreads();
        partK[t] += vK; partS[t] += vS;
        __syncthreads();
    }
    int exK = (t == 0) ? 0 : partK[t - 1];
    int exS = (t == 0) ? 0 : partS[t - 1];
#pragma unroll
    for (int j = 0; j < PER; ++j) {
        int idx = base + j;
        if (idx >= NBINS_) continue;
        int off = exK + localK[j];
        int sb  = exS + localS[j];
        binOff[idx] = off;
        int k = binCnt[idx];
        int nseg = (k + SEG_ - 1) / SEG_; if (nseg == 0) nseg = 1;
        for (int q = 0; q < nseg; ++q) {
            int len = k - q * SEG_;
            len = (len < 0) ? 0 : ((len > SEG_) ? SEG_ : len);
            segs[sb + q] = make_int4(idx, off + q * SEG_, len, nseg);
        }
    }
    if (t == 0) segTotal[0] = partS[1023];
}

// ---------------- Kernel P: pack points into bin order, pre-scale weights --
__global__ __launch_bounds__(256) void pack_kernel(
    const int* __restrict__ pixA, const int* __restrict__ idA,
    const float* __restrict__ wA, const float* __restrict__ cnt,
    const int* __restrict__ binOff, int* __restrict__ binFill,
    int4* __restrict__ idP, float4* __restrict__ wP)
{
    int g = blockIdx.x * 256 + threadIdx.x;
    int b = g >> 14;                     // N_ = 16384
    int pix = pixA[g];
    int u = pix % W_IMG, v = pix / W_IMG;
    int bin = b * NBLK_ + (v >> 2) * OW_ + (u >> 2);
    int pos = atomicAdd(&binFill[bin], 1);
    int dst = binOff[bin] + pos;
    float s = 0.0625f / fmaxf(cnt[b * HW_ + pix], 1.0f);
    idP[dst] = make_int4(idA[g], idA[g + NT_], idA[g + 2 * NT_], b);
    wP[dst]  = make_float4(wA[g] * s, wA[g + NT_] * s, wA[g + 2 * NT_] * s, 0.0f);
}

// ---------------- Kernel G: per-segment gather-reduce into bin-major tmp ---
// Bin-major stores: 64 consecutive lanes = contiguous 1KB => zero inflation.
// 4 accumulators + unroll-4: ~12 gather loads in flight (L2-latency hiding).
__global__ __launch_bounds__(256) void gather_kernel(
    const float* __restrict__ XT, const int4* __restrict__ segs,
    const int* __restrict__ segTotal, const int4* __restrict__ idP,
    const float4* __restrict__ wP, float* __restrict__ tmp)
{
    int sid = blockIdx.x;
    if (sid >= segTotal[0]) return;
    int4 sg   = segs[sid];
    int bin   = sg.x, start = sg.y, len = sg.z, nseg = sg.w;
    int b     = bin / NBLK_;
    int c     = threadIdx.x;

    __shared__ int4   sId[SEG_];
    __shared__ float4 sW [SEG_];
    if (c < len) { sId[c] = idP[start + c]; sW[c] = wP[start + c]; }
    __syncthreads();

    const float* XTb = XT + (size_t)b * (M_ * C_);
    float a0 = 0.0f, a1 = 0.0f, a2 = 0.0f, a3 = 0.0f;
    int j = 0;
    for (; j + 3 < len; j += 4) {
        int4 iA = sId[j];     float4 wAa = sW[j];
        int4 iB = sId[j + 1]; float4 wBb = sW[j + 1];
        int4 iC = sId[j + 2]; float4 wCc = sW[j + 2];
        int4 iD = sId[j + 3]; float4 wDd = sW[j + 3];
        a0 = fmaf(wAa.x, XTb[iA.x * C_ + c],
             fmaf(wAa.y, XTb[iA.y * C_ + c],
             fmaf(wAa.z, XTb[iA.z * C_ + c], a0)));
        a1 = fmaf(wBb.x, XTb[iB.x * C_ + c],
             fmaf(wBb.y, XTb[iB.y * C_ + c],
             fmaf(wBb.z, XTb[iB.z * C_ + c], a1)));
        a2 = fmaf(wCc.x, XTb[iC.x * C_ + c],
             fmaf(wCc.y, XTb[iC.y * C_ + c],
             fmaf(wCc.z, XTb[iC.z * C_ + c], a2)));
        a3 = fmaf(wDd.x, XTb[iD.x * C_ + c],
             fmaf(wDd.y, XTb[iD.y * C_ + c],
             fmaf(wDd.z, XTb[iD.z * C_ + c], a3)));
    }
    for (; j < len; ++j) {
        int4 iA = sId[j]; float4 wAa = sW[j];
        a0 = fmaf(wAa.x, XTb[iA.x * C_ + c],
             fmaf(wAa.y, XTb[iA.y * C_ + c],
             fmaf(wAa.z, XTb[iA.z * C_ + c], a0)));
    }
    float acc = (a0 + a1) + (a2 + a3);

    float* dst = &tmp[(size_t)bin * C_ + c];
    if (nseg == 1) *dst = acc;            // covers empty bins (acc = 0)
    else           atomicAdd(dst, acc);   // tmp pre-zeroed in transpose_kernel
}

// ---------------- Kernel U: untranspose tmp (B,NBLK,C) -> out (B,C,NBLK) ---
__global__ __launch_bounds__(1024) void untranspose_kernel(
    const float* __restrict__ tmp, float* __restrict__ out)
{
    __shared__ float tile[32][33];
    int b  = blockIdx.z;
    int n0 = blockIdx.x * 32;   // NBLK_/32 = 98
    int c0 = blockIdx.y * 32;   // C_/32 = 8
    int tx = threadIdx.x, ty = threadIdx.y;
    tile[ty][tx] = tmp[((size_t)b * NBLK_ + n0 + ty) * C_ + c0 + tx];
    __syncthreads();
    out[((size_t)(b * C_ + c0 + ty)) * NBLK_ + n0 + tx] = tile[tx][ty];
}

extern "C" void kernel_launch(void* const* d_in, const int* in_sizes, int n_in,
                              void* d_out, int out_size, void* d_ws, size_t ws_size,
                              hipStream_t stream)
{
    const float* xyz_feats = (const float*)d_in[0];  // (B,C,M)
    const float* points    = (const float*)d_in[1];  // (B,N,3)
    const float* centers   = (const float*)d_in[2];  // (B,M,3)
    const float* Kmat      = (const float*)d_in[3];  // (3,3)

    float* out = (float*)d_out;

    // workspace layout (~21.7 MB)
    float*  XT       = (float*)d_ws;                         // 4 MB
    int4*   idP      = (int4*)(XT + (size_t)B_ * M_ * C_);   // 1 MB
    float4* wP       = (float4*)(idP + NT_);                 // 1 MB
    int4*   segs     = (int4*)(wP + NT_);                    // 228 KB
    float*  tmp      = (float*)(segs + MAXSEG_);             // 12.8 MB (zero rgn)
    float*  cnt      = tmp + (size_t)NBINS_ * C_;            // 784 KB
    int*    binCnt   = (int*)(cnt + (size_t)B_ * HW_);       // 50 KB
    int*    binFill  = binCnt + NBINS_;                      // 50 KB
    int*    segTotal = binFill + NBINS_;                     // 4 B
    int*    pixA     = segTotal + 1;                         // 256 KB
    int*    idA      = pixA + NT_;                           // 768 KB
    float*  wA       = (float*)(idA + 3 * NT_);              // 768 KB
    int*    binOff   = (int*)(wA + 3 * NT_);                 // 50 KB

    dim3 tb(32, 32);
    dim3 tg(C_ / 32, M_ / 32, B_);
    transpose_kernel<<<tg, tb, 0, stream>>>(xyz_feats, XT, tmp);

    dim3 bg(N_ / PTS_, B_);   // 128 x 4 = 512 blocks, 2 blocks/CU
    top3_kernel<<<bg, 1024, 0, stream>>>(points, centers, Kmat,
                                         pixA, idA, wA, cnt, binCnt);

    scan_kernel<<<1, 1024, 0, stream>>>(binCnt, binOff, segs, segTotal);

    pack_kernel<<<NT_ / 256, 256, 0, stream>>>(pixA, idA, wA, cnt,
                                               binOff, binFill, idP, wP);

    gather_kernel<<<MAXSEG_, 256, 0, stream>>>(XT, segs, segTotal,
                                               idP, wP, tmp);

    dim3 ug(NBLK_ / 32, C_ / 32, B_);
    untranspose_kernel<<<ug, tb, 0, stream>>>(tmp, out);
}